// Round 8
// baseline (194.391 us; speedup 1.0000x reference)
//
#include <hip/hip_runtime.h>
#include <stdint.h>

#define DM 1024
#define NH 16
#define HD 64
#define BB 2
#define TT 2048
#define MT (BB*TT)   // 4096 rows total

typedef __bf16 bfrag __attribute__((ext_vector_type(8)));     // 8 bf16 = 4 VGPR (MFMA A/B)
typedef float  f32x4 __attribute__((ext_vector_type(4)));     // MFMA C/D

__device__ __forceinline__ unsigned short f2bf(float f) {
  union { float f; unsigned u; } v; v.f = f;
  unsigned r = v.u + 0x7fffu + ((v.u >> 16) & 1u);  // RNE
  return (unsigned short)(r >> 16);
}

__device__ __forceinline__ unsigned short f2bf_hw(float f) {
  __bf16 b = (__bf16)f;                 // hardware cvt
  union { __bf16 b; unsigned short u; } v; v.b = b;
  return v.u;
}

__device__ __forceinline__ unsigned int pack2bf(float a, float b) {
  union { __bf16 h[2]; unsigned int u; } v;
  v.h[0] = (__bf16)a; v.h[1] = (__bf16)b;   // fuses to v_cvt_pk_bf16_f32
  return v.u;
}

__device__ __forceinline__ void async16(const void* g, void* l) {
  __builtin_amdgcn_global_load_lds(
      (const __attribute__((address_space(1))) unsigned int*)g,
      (__attribute__((address_space(3))) unsigned int*)l, 16, 0, 0);
}

// ---------------------------------------------------------------- cvt fp32->bf16
__global__ __launch_bounds__(256) void cvt_kernel(
    const float* __restrict__ x,  const float* __restrict__ Wq,
    const float* __restrict__ Wk, const float* __restrict__ Wv,
    const float* __restrict__ Wo,
    unsigned short* __restrict__ xb, unsigned short* __restrict__ wqkv,
    unsigned short* __restrict__ wob) {
  int i = blockIdx.x * 256 + threadIdx.x;       // one float4 group each
  const int NX = MT * DM / 4;                   // 1048576 groups of x
  const int NW = DM * DM / 4;                   // 262144 per weight
  const float* src; unsigned short* dst; int off;
  if      (i < NX)        { src = x;  dst = xb;              off = i; }
  else if (i < NX + NW)   { src = Wq; dst = wqkv;            off = i - NX; }
  else if (i < NX + 2*NW) { src = Wk; dst = wqkv + DM*DM;    off = i - NX - NW; }
  else if (i < NX + 3*NW) { src = Wv; dst = wqkv + 2*DM*DM;  off = i - NX - 2*NW; }
  else                    { src = Wo; dst = wob;             off = i - NX - 3*NW; }
  float4 v = ((const float4*)src)[off];
  ushort4 o;
  o.x = f2bf(v.x); o.y = f2bf(v.y); o.z = f2bf(v.z); o.w = f2bf(v.w);
  ((ushort4*)dst)[off] = o;
}

// ---------------------------------------------------------------- GEMM C = A * B^T
// r5-exact (best measured: QKV 51 us / 506 TF). TM x 128 tile, BK=32, dbuf LDS,
// ONE barrier per K-step, bank swizzle chunk = quad ^ ((row>>1)&3) (conflict-free).
// Structural plateau: __syncthreads drains vmcnt(0) each step (m97 ceiling).
template<int EPI, int TM>
__global__ __launch_bounds__(256) void gemm_bt(
    const unsigned short* __restrict__ A, const unsigned short* __restrict__ Bm,
    const float* __restrict__ bias0, const float* __restrict__ bias1,
    const float* __restrict__ bias2,
    unsigned short* __restrict__ Qo, unsigned short* __restrict__ Ko,
    unsigned short* __restrict__ Vo, float* __restrict__ Co) {
  constexpr int WM = TM / 2;       // rows per wave
  constexpr int MI = WM / 16;      // acc tiles along M
  const int tid = threadIdx.x;
  const int wave = tid >> 6, lane = tid & 63;
  const int lr = lane & 15, quad = lane >> 4;
  const int m0 = blockIdx.y * TM, n0 = blockIdx.x * 128;
  __shared__ __align__(16) unsigned short sA[2][TM * 32];
  __shared__ __align__(16) unsigned short sB[2][128 * 32];
  const f32x4 zero = {0.f, 0.f, 0.f, 0.f};
  f32x4 acc[MI][4];
#pragma unroll
  for (int i = 0; i < MI; i++)
#pragma unroll
    for (int j = 0; j < 4; j++) acc[i][j] = zero;
  const int wm = (wave >> 1) * WM, wn = (wave & 1) * 64;

  auto stage = [&](int kt, int buf) {
    const int k0 = kt * 32;
#pragma unroll
    for (int rep = 0; rep < TM / 64; ++rep) {
      int fb = rep * 2048 + wave * 512;     // wave-uniform LDS base (elements)
      int fl = fb + lane * 8;
      int row = fl >> 5;
      int c   = (fl >> 3) & 3;
      int col = ((c ^ ((row >> 1) & 3)) << 3);  // bank swizzle folded into gaddr
      async16(A + (size_t)(m0 + row) * 1024 + k0 + col, &sA[buf][fb]);
    }
#pragma unroll
    for (int rep = 0; rep < 2; ++rep) {
      int fb = rep * 2048 + wave * 512;
      int fl = fb + lane * 8;
      int row = fl >> 5;
      int c   = (fl >> 3) & 3;
      int col = ((c ^ ((row >> 1) & 3)) << 3);
      async16(Bm + (size_t)(n0 + row) * 1024 + k0 + col, &sB[buf][fb]);
    }
  };

  stage(0, 0);
  for (int kt = 0; kt < 32; ++kt) {
    const int buf = kt & 1;
    __syncthreads();                 // staged tile kt visible; prev compute done
    if (kt + 1 < 32) stage(kt + 1, buf ^ 1);
    bfrag af[MI], bfr[4];
#pragma unroll
    for (int i = 0; i < MI; i++) {
      int ra = wm + i * 16 + lr;
      af[i]  = *(const bfrag*)&sA[buf][ra * 32 + ((quad ^ ((ra >> 1) & 3)) << 3)];
    }
#pragma unroll
    for (int j = 0; j < 4; j++) {
      int rb = wn + j * 16 + lr;
      bfr[j] = *(const bfrag*)&sB[buf][rb * 32 + ((quad ^ ((rb >> 1) & 3)) << 3)];
    }
#pragma unroll
    for (int i = 0; i < MI; i++)
#pragma unroll
      for (int j = 0; j < 4; j++)
        acc[i][j] = __builtin_amdgcn_mfma_f32_16x16x32_bf16(af[i], bfr[j], acc[i][j], 0, 0, 0);
  }

  if (EPI == 0) {
    // n in [0,3072): qkv = n>>10; head h = (n&1023)>>6; d = n&63
#pragma unroll
    for (int j = 0; j < 4; j++) {
      int n = n0 + wn + j * 16 + lr;
      int qkv = n >> 10, nn = n & 1023;
      float bias = (qkv == 0 ? bias0 : qkv == 1 ? bias1 : bias2)[nn];
      int h = nn >> 6, d = nn & 63;
      if (qkv == 2) {
        // V: no rotary; fragment-order layout, pack 4 consecutive keys (r) per store
#pragma unroll
        for (int i = 0; i < MI; i++) {
          int t0 = m0 + wm + i * 16 + quad * 4;
          int b = t0 >> 11, tt = t0 & 2047;
          size_t bb = (size_t)((b << 4) + h) * (TT * 64);
          int kk0 = tt & 63;
          size_t off = bb + (size_t)(tt >> 6) * 4096 +
                       (size_t)((kk0 >> 3) << 9) + (d << 3) + (kk0 & 7);
          ushort4 pk;
          pk.x = f2bf(acc[i][j][0] + bias);
          pk.y = f2bf(acc[i][j][1] + bias);
          pk.z = f2bf(acc[i][j][2] + bias);
          pk.w = f2bf(acc[i][j][3] + bias);
          *(ushort4*)(Vo + off) = pk;
        }
      } else {
#pragma unroll
        for (int i = 0; i < MI; i++)
#pragma unroll
          for (int r = 0; r < 4; r++) {
            int m = m0 + wm + i * 16 + quad * 4 + r;
            float vb = acc[i][j][r] + bias;
            // rotary pair (d^1) lives in lane^1 (same row, adjacent column)
            float pv = __shfl_xor(vb, 1);
            float val = (n & 1) ? pv : -pv;
            int b = m >> 11, t = m & 2047;
            size_t base = (size_t)((b << 4) + h) * (TT * 64);
            if (qkv == 0) {                       // Q: plain (B,H,T,64), pre-scaled
              Qo[base + (size_t)t * 64 + d] = f2bf(val * 0.125f);
            } else {                              // K: fragment-order per 64-row tile
              int kk = t & 63;
              size_t off = base + (size_t)(t >> 6) * 4096 +
                           (size_t)((d >> 3) << 9) + (kk << 3) + (d & 7);
              Ko[off] = f2bf(val);
            }
          }
      }
    }
  } else {
#pragma unroll
    for (int j = 0; j < 4; j++) {
      int n = n0 + wn + j * 16 + lr;
      float bias = bias0[n];
#pragma unroll
      for (int i = 0; i < MI; i++)
#pragma unroll
        for (int r = 0; r < 4; r++) {
          int m = m0 + wm + i * 16 + quad * 4 + r;
          Co[(size_t)m * 1024 + n] = acc[i][j][r] + bias;
        }
    }
  }
}

// ---------------------------------------------------------------- flash attention
// Block = 512 threads (8 waves), Q-tile PAIR (qt=p, 31-p). Waves 0-3 own the
// LONG stream (qt=31-p, active all nB steps), waves 4-7 the SHORT one (qt=p,
// active nS=p+1 steps). Same total work/staging as the 4-wave version but
// 16 resident waves/CU (4/SIMD) for stall overlap. S^T = mfma(K,Q) (lane&15=q),
// fixed-max softmax (m=11, no cross-lane reduces), per-wave P^T LDS roundtrip,
// PV = mfma(V^T, P^T) accumulating O^T; l = scalar/lane reduced once at end.
__global__ __launch_bounds__(512, 4) void flash_kernel(
    const unsigned short* __restrict__ Qg, const unsigned short* __restrict__ Kg,
    const unsigned short* __restrict__ Vg, unsigned short* __restrict__ Og) {
  const int p = blockIdx.x;                 // 0..15
  const int bh = blockIdx.y;
  const int tid = threadIdx.x, wave = tid >> 6, lane = tid & 63;
  const int lr = lane & 15, quad = lane >> 4;
  __shared__ __align__(16) unsigned short sK[2][4096];
  __shared__ __align__(16) unsigned short sV[2][4096];
  __shared__ __align__(16) unsigned short sP[8][1024];   // per-wave P^T buffer
  const size_t base = (size_t)bh * (TT * 64);
  const int st = wave >> 2;                 // 0 = long stream, 1 = short stream
  const int qt = st ? p : (31 - p);
  const int nS = st ? (p + 1) : (32 - p);   // active steps for this wave
  const int nB = 32 - p;                    // block step count (long stream)
  const int qg = qt * 64 + (wave & 3) * 16 + lr;   // this lane's q row
  const f32x4 zero = {0.f, 0.f, 0.f, 0.f};

  bfrag qf0, qf1;
  {
    const unsigned short* qr = Qg + base + (size_t)qg * 64;
    qf0 = *(const bfrag*)(qr + quad * 8);
    qf1 = *(const bfrag*)(qr + 32 + quad * 8);
  }
  f32x4 o[4];
  float rs = 0.f;
#pragma unroll
  for (int j = 0; j < 4; j++) o[j] = zero;

  const unsigned short* kgb = Kg + base;
  const unsigned short* vgb = Vg + base;

  // stage tile 0 into buf 0: each of 8 waves stages 1KB of K and 1KB of V
  {
    int fb = wave * 512;
    async16(kgb + fb + lane * 8, &sK[0][fb]);
    async16(vgb + fb + lane * 8, &sV[0][fb]);
  }

  unsigned short* sPw = sP[wave];
  const int pwr = lr * 8 + (quad & 1) * 4;  // P-write column part
  const int pq2 = quad >> 1;

  for (int kt = 0; kt < nB; ++kt) {
    const int buf = kt & 1;
    __syncthreads();                        // staged tile kt ready; prev compute done
    if (kt + 1 < nB) {                      // prefetch next tile into other buffer
      int fb = wave * 512;
      const size_t g = (size_t)(kt + 1) * 4096 + fb + lane * 8;
      async16(kgb + g, &sK[buf ^ 1][fb]);
      async16(vgb + g, &sV[buf ^ 1][fb]);
    }
    if (kt < nS) {                          // wave-uniform; short-stream waves idle late
      // S^T: lane&15 = q, rows = keys (frag reads inlined to cap VGPR)
      f32x4 sT[4];
#pragma unroll
      for (int ct = 0; ct < 4; ct++) {
        int row8 = (ct * 16 + lr) * 8;
        bfrag k0 = *(const bfrag*)&sK[buf][quad * 512 + row8];
        bfrag k1 = *(const bfrag*)&sK[buf][(4 + quad) * 512 + row8];
        f32x4 t = __builtin_amdgcn_mfma_f32_16x16x32_bf16(k0, qf0, zero, 0, 0, 0);
        sT[ct]  = __builtin_amdgcn_mfma_f32_16x16x32_bf16(k1, qf1, t,    0, 0, 0);
      }
      const bool diag = (kt == nS - 1);
#pragma unroll
      for (int ct = 0; ct < 4; ++ct) {
        float e[4];
#pragma unroll
        for (int r = 0; r < 4; ++r)
          e[r] = __expf(sT[ct][r] - 11.0f);   // fixed max m=11
        if (diag) {
#pragma unroll
          for (int r = 0; r < 4; ++r) {
            int key = kt * 64 + ct * 16 + quad * 4 + r;
            if (key > qg) e[r] = 0.f;
          }
        }
        rs += (e[0] + e[1]) + (e[2] + e[3]);
        uint2 w;
        w.x = pack2bf(e[0], e[1]);
        w.y = pack2bf(e[2], e[3]);
        *(uint2*)&sPw[(ct * 2 + pq2) * 128 + pwr] = w;   // P^T chunk-major
      }
      bfrag pf0 = *(const bfrag*)&sPw[quad * 128 + lr * 8];        // keys 0-31
      bfrag pf1 = *(const bfrag*)&sPw[(4 + quad) * 128 + lr * 8];  // keys 32-63
#pragma unroll
      for (int j = 0; j < 4; j++) {
        int row8 = (j * 16 + lr) * 8;
        bfrag v0 = *(const bfrag*)&sV[buf][quad * 512 + row8];     // A-frag m=d
        bfrag v1 = *(const bfrag*)&sV[buf][(4 + quad) * 512 + row8];
        o[j] = __builtin_amdgcn_mfma_f32_16x16x32_bf16(v0, pf0, o[j], 0, 0, 0);
        o[j] = __builtin_amdgcn_mfma_f32_16x16x32_bf16(v1, pf1, o[j], 0, 0, 0);
      }
    }
  }

  // final l reduce across quads (lanes lr, lr+16, lr+32, lr+48 share q)
  rs += __shfl_xor(rs, 16); rs += __shfl_xor(rs, 32);
  const float inv = 1.0f / rs;

  // epilogue: O^T (lane=q, regs=d) -> (B,T,D) bf16, 8B packed stores
  const int b = bh >> 4, h = bh & 15;
#pragma unroll
  for (int j = 0; j < 4; j++) {
    ushort4 pk;
    pk.x = f2bf_hw(o[j][0] * inv); pk.y = f2bf_hw(o[j][1] * inv);
    pk.z = f2bf_hw(o[j][2] * inv); pk.w = f2bf_hw(o[j][3] * inv);
    int col = h * 64 + j * 16 + quad * 4;
    *(ushort4*)(Og + (size_t)(b * TT + qg) * 1024 + col) = pk;
  }
}

// ---------------------------------------------------------------- launch
extern "C" void kernel_launch(void* const* d_in, const int* in_sizes, int n_in,
                              void* d_out, int out_size, void* d_ws, size_t ws_size,
                              hipStream_t stream) {
  const float* x  = (const float*)d_in[0];
  const float* Wq = (const float*)d_in[1];
  const float* bq = (const float*)d_in[2];
  const float* Wk = (const float*)d_in[3];
  const float* bk = (const float*)d_in[4];
  const float* Wv = (const float*)d_in[5];
  const float* bv = (const float*)d_in[6];
  const float* Wo = (const float*)d_in[7];
  const float* bo = (const float*)d_in[8];
  float* out = (float*)d_out;

  unsigned short* ws = (unsigned short*)d_ws;
  unsigned short* xb   = ws;                                // 4M elems
  unsigned short* wqkv = ws + (size_t)4 * 1024 * 1024;      // 3M
  unsigned short* wob  = ws + (size_t)7 * 1024 * 1024;      // 1M
  unsigned short* Qb   = ws + (size_t)8 * 1024 * 1024;      // 4M
  unsigned short* Kb   = ws + (size_t)12 * 1024 * 1024;     // 4M
  unsigned short* Vb   = ws + (size_t)16 * 1024 * 1024;     // 4M
  unsigned short* Ob   = ws + (size_t)20 * 1024 * 1024;     // 4M -> 48MB total

  cvt_kernel<<<dim3(8192), dim3(256), 0, stream>>>(x, Wq, Wk, Wv, Wo, xb, wqkv, wob);
  gemm_bt<0, 128><<<dim3(24, 32), dim3(256), 0, stream>>>(xb, wqkv, bq, bk, bv,
                                                          Qb, Kb, Vb, (float*)nullptr);
  flash_kernel<<<dim3(16, 32), dim3(512), 0, stream>>>(Qb, Kb, Vb, Ob);
  gemm_bt<1, 64><<<dim3(8, 64), dim3(256), 0, stream>>>(Ob, wob, bo, nullptr, nullptr,
                                                        nullptr, nullptr, nullptr, out);
}

// Round 9
// 191.945 us; speedup vs baseline: 1.0127x; 1.0127x over previous
//
#include <hip/hip_runtime.h>
#include <stdint.h>

#define DM 1024
#define NH 16
#define HD 64
#define BB 2
#define TT 2048
#define MT (BB*TT)   // 4096 rows total

typedef __bf16 bfrag __attribute__((ext_vector_type(8)));     // 8 bf16 = 4 VGPR (MFMA A/B)
typedef float  f32x4 __attribute__((ext_vector_type(4)));     // MFMA C/D

__device__ __forceinline__ unsigned short f2bf(float f) {
  union { float f; unsigned u; } v; v.f = f;
  unsigned r = v.u + 0x7fffu + ((v.u >> 16) & 1u);  // RNE
  return (unsigned short)(r >> 16);
}

__device__ __forceinline__ unsigned short f2bf_hw(float f) {
  __bf16 b = (__bf16)f;                 // hardware cvt
  union { __bf16 b; unsigned short u; } v; v.b = b;
  return v.u;
}

__device__ __forceinline__ unsigned int pack2bf(float a, float b) {
  union { __bf16 h[2]; unsigned int u; } v;
  v.h[0] = (__bf16)a; v.h[1] = (__bf16)b;   // fuses to v_cvt_pk_bf16_f32
  return v.u;
}

__device__ __forceinline__ void async16(const void* g, void* l) {
  __builtin_amdgcn_global_load_lds(
      (const __attribute__((address_space(1))) unsigned int*)g,
      (__attribute__((address_space(3))) unsigned int*)l, 16, 0, 0);
}

// ---------------------------------------------------------------- cvt fp32->bf16
__global__ __launch_bounds__(256) void cvt_kernel(
    const float* __restrict__ x,  const float* __restrict__ Wq,
    const float* __restrict__ Wk, const float* __restrict__ Wv,
    const float* __restrict__ Wo,
    unsigned short* __restrict__ xb, unsigned short* __restrict__ wqkv,
    unsigned short* __restrict__ wob) {
  int i = blockIdx.x * 256 + threadIdx.x;       // one float4 group each
  const int NX = MT * DM / 4;                   // 1048576 groups of x
  const int NW = DM * DM / 4;                   // 262144 per weight
  const float* src; unsigned short* dst; int off;
  if      (i < NX)        { src = x;  dst = xb;              off = i; }
  else if (i < NX + NW)   { src = Wq; dst = wqkv;            off = i - NX; }
  else if (i < NX + 2*NW) { src = Wk; dst = wqkv + DM*DM;    off = i - NX - NW; }
  else if (i < NX + 3*NW) { src = Wv; dst = wqkv + 2*DM*DM;  off = i - NX - 2*NW; }
  else                    { src = Wo; dst = wob;             off = i - NX - 3*NW; }
  float4 v = ((const float4*)src)[off];
  ushort4 o;
  o.x = f2bf(v.x); o.y = f2bf(v.y); o.z = f2bf(v.z); o.w = f2bf(v.w);
  ((ushort4*)dst)[off] = o;
}

// ---------------------------------------------------------------- QKV GEMM (r5-exact)
// C = A * B^T, 128x128 tile, BK=32, dbuf LDS, ONE barrier per K-step.
// Bank swizzle chunk = quad ^ ((row>>1)&3) (conflict-free, measured r5/r8).
template<int EPI, int TM>
__global__ __launch_bounds__(256) void gemm_bt(
    const unsigned short* __restrict__ A, const unsigned short* __restrict__ Bm,
    const float* __restrict__ bias0, const float* __restrict__ bias1,
    const float* __restrict__ bias2,
    unsigned short* __restrict__ Qo, unsigned short* __restrict__ Ko,
    unsigned short* __restrict__ Vo, float* __restrict__ Co) {
  constexpr int WM = TM / 2;       // rows per wave
  constexpr int MI = WM / 16;      // acc tiles along M
  const int tid = threadIdx.x;
  const int wave = tid >> 6, lane = tid & 63;
  const int lr = lane & 15, quad = lane >> 4;
  const int m0 = blockIdx.y * TM, n0 = blockIdx.x * 128;
  __shared__ __align__(16) unsigned short sA[2][TM * 32];
  __shared__ __align__(16) unsigned short sB[2][128 * 32];
  const f32x4 zero = {0.f, 0.f, 0.f, 0.f};
  f32x4 acc[MI][4];
#pragma unroll
  for (int i = 0; i < MI; i++)
#pragma unroll
    for (int j = 0; j < 4; j++) acc[i][j] = zero;
  const int wm = (wave >> 1) * WM, wn = (wave & 1) * 64;

  auto stage = [&](int kt, int buf) {
    const int k0 = kt * 32;
#pragma unroll
    for (int rep = 0; rep < TM / 64; ++rep) {
      int fb = rep * 2048 + wave * 512;     // wave-uniform LDS base (elements)
      int fl = fb + lane * 8;
      int row = fl >> 5;
      int c   = (fl >> 3) & 3;
      int col = ((c ^ ((row >> 1) & 3)) << 3);  // bank swizzle folded into gaddr
      async16(A + (size_t)(m0 + row) * 1024 + k0 + col, &sA[buf][fb]);
    }
#pragma unroll
    for (int rep = 0; rep < 2; ++rep) {
      int fb = rep * 2048 + wave * 512;
      int fl = fb + lane * 8;
      int row = fl >> 5;
      int c   = (fl >> 3) & 3;
      int col = ((c ^ ((row >> 1) & 3)) << 3);
      async16(Bm + (size_t)(n0 + row) * 1024 + k0 + col, &sB[buf][fb]);
    }
  };

  stage(0, 0);
  for (int kt = 0; kt < 32; ++kt) {
    const int buf = kt & 1;
    __syncthreads();                 // staged tile kt visible; prev compute done
    if (kt + 1 < 32) stage(kt + 1, buf ^ 1);
    bfrag af[MI], bfr[4];
#pragma unroll
    for (int i = 0; i < MI; i++) {
      int ra = wm + i * 16 + lr;
      af[i]  = *(const bfrag*)&sA[buf][ra * 32 + ((quad ^ ((ra >> 1) & 3)) << 3)];
    }
#pragma unroll
    for (int j = 0; j < 4; j++) {
      int rb = wn + j * 16 + lr;
      bfr[j] = *(const bfrag*)&sB[buf][rb * 32 + ((quad ^ ((rb >> 1) & 3)) << 3)];
    }
#pragma unroll
    for (int i = 0; i < MI; i++)
#pragma unroll
      for (int j = 0; j < 4; j++)
        acc[i][j] = __builtin_amdgcn_mfma_f32_16x16x32_bf16(af[i], bfr[j], acc[i][j], 0, 0, 0);
  }

  if (EPI == 0) {
    // n in [0,3072): qkv = n>>10; head h = (n&1023)>>6; d = n&63
#pragma unroll
    for (int j = 0; j < 4; j++) {
      int n = n0 + wn + j * 16 + lr;
      int qkv = n >> 10, nn = n & 1023;
      float bias = (qkv == 0 ? bias0 : qkv == 1 ? bias1 : bias2)[nn];
      int h = nn >> 6, d = nn & 63;
      if (qkv == 2) {
        // V: no rotary; fragment-order layout, pack 4 consecutive keys (r) per store
#pragma unroll
        for (int i = 0; i < MI; i++) {
          int t0 = m0 + wm + i * 16 + quad * 4;
          int b = t0 >> 11, tt = t0 & 2047;
          size_t bb = (size_t)((b << 4) + h) * (TT * 64);
          int kk0 = tt & 63;
          size_t off = bb + (size_t)(tt >> 6) * 4096 +
                       (size_t)((kk0 >> 3) << 9) + (d << 3) + (kk0 & 7);
          ushort4 pk;
          pk.x = f2bf(acc[i][j][0] + bias);
          pk.y = f2bf(acc[i][j][1] + bias);
          pk.z = f2bf(acc[i][j][2] + bias);
          pk.w = f2bf(acc[i][j][3] + bias);
          *(ushort4*)(Vo + off) = pk;
        }
      } else {
#pragma unroll
        for (int i = 0; i < MI; i++)
#pragma unroll
          for (int r = 0; r < 4; r++) {
            int m = m0 + wm + i * 16 + quad * 4 + r;
            float vb = acc[i][j][r] + bias;
            // rotary pair (d^1) lives in lane^1 (same row, adjacent column)
            float pv = __shfl_xor(vb, 1);
            float val = (n & 1) ? pv : -pv;
            int b = m >> 11, t = m & 2047;
            size_t base = (size_t)((b << 4) + h) * (TT * 64);
            if (qkv == 0) {                       // Q: plain (B,H,T,64), pre-scaled
              Qo[base + (size_t)t * 64 + d] = f2bf(val * 0.125f);
            } else {                              // K: fragment-order per 64-row tile
              int kk = t & 63;
              size_t off = base + (size_t)(t >> 6) * 4096 +
                           (size_t)((d >> 3) << 9) + (kk << 3) + (d & 7);
              Ko[off] = f2bf(val);
            }
          }
      }
    }
  } else {
#pragma unroll
    for (int j = 0; j < 4; j++) {
      int n = n0 + wn + j * 16 + lr;
      float bias = bias0[n];
#pragma unroll
      for (int i = 0; i < MI; i++)
#pragma unroll
        for (int r = 0; r < 4; r++) {
          int m = m0 + wm + i * 16 + quad * 4 + r;
          Co[(size_t)m * 1024 + n] = acc[i][j][r] + bias;
        }
    }
  }
}

// ---------------------------------------------------------------- out-proj GEMM
// C = A * B^T + bias, fp32 out. 64x128 tile, BK=64: each staged tile feeds TWO
// MFMA K-windows -> 16 barriers (vs 32) with 16 MFMA/wave each. The kernel is
// barrier-latency-bound, so halving barrier count ~halves wall time.
// Rows are 64 elems = 128 B: bank group = chunk (8 groups); swizzle
// chunk ^= ((row&1)<<2)|((row>>1)&3) -> 8 distinct groups per 8-lane phase.
__global__ __launch_bounds__(256) void gemm_op(
    const unsigned short* __restrict__ A, const unsigned short* __restrict__ Bm,
    const float* __restrict__ bias0, float* __restrict__ Co) {
  const int tid = threadIdx.x;
  const int wave = tid >> 6, lane = tid & 63;
  const int lr = lane & 15, quad = lane >> 4;
  const int m0 = blockIdx.y * 64, n0 = blockIdx.x * 128;
  __shared__ __align__(16) unsigned short sA[2][64 * 64];
  __shared__ __align__(16) unsigned short sB[2][128 * 64];
  const f32x4 zero = {0.f, 0.f, 0.f, 0.f};
  f32x4 acc[2][4];
#pragma unroll
  for (int i = 0; i < 2; i++)
#pragma unroll
    for (int j = 0; j < 4; j++) acc[i][j] = zero;
  const int wm = (wave >> 1) * 32, wn = (wave & 1) * 64;

  auto swz = [](int row) { return ((row & 1) << 2) | ((row >> 1) & 3); };

  auto stage = [&](int kt, int buf) {
    const int k0 = kt * 64;
#pragma unroll
    for (int rep = 0; rep < 2; ++rep) {       // A: 64 rows x 64
      int fb = rep * 2048 + wave * 512;
      int fl = fb + lane * 8;
      int row = fl >> 6, pc = (fl >> 3) & 7;
      async16(A + (size_t)(m0 + row) * 1024 + k0 + ((pc ^ swz(row)) << 3), &sA[buf][fb]);
    }
#pragma unroll
    for (int rep = 0; rep < 4; ++rep) {       // B: 128 rows x 64
      int fb = rep * 2048 + wave * 512;
      int fl = fb + lane * 8;
      int row = fl >> 6, pc = (fl >> 3) & 7;
      async16(Bm + (size_t)(n0 + row) * 1024 + k0 + ((pc ^ swz(row)) << 3), &sB[buf][fb]);
    }
  };

  stage(0, 0);
  for (int kt = 0; kt < 16; ++kt) {
    const int buf = kt & 1;
    __syncthreads();                 // staged tile kt visible; prev compute done
    if (kt + 1 < 16) stage(kt + 1, buf ^ 1);
#pragma unroll
    for (int ks = 0; ks < 2; ++ks) {          // two 32-K windows per staged tile
      bfrag af[2], bfr[4];
#pragma unroll
      for (int i = 0; i < 2; i++) {
        int ra = wm + i * 16 + lr;
        af[i] = *(const bfrag*)&sA[buf][ra * 64 + (((ks * 4 + quad) ^ swz(ra)) << 3)];
      }
#pragma unroll
      for (int j = 0; j < 4; j++) {
        int rb = wn + j * 16 + lr;
        bfr[j] = *(const bfrag*)&sB[buf][rb * 64 + (((ks * 4 + quad) ^ swz(rb)) << 3)];
      }
#pragma unroll
      for (int i = 0; i < 2; i++)
#pragma unroll
        for (int j = 0; j < 4; j++)
          acc[i][j] = __builtin_amdgcn_mfma_f32_16x16x32_bf16(af[i], bfr[j], acc[i][j], 0, 0, 0);
    }
  }

#pragma unroll
  for (int j = 0; j < 4; j++) {
    int n = n0 + wn + j * 16 + lr;
    float bias = bias0[n];
#pragma unroll
    for (int i = 0; i < 2; i++)
#pragma unroll
      for (int r = 0; r < 4; r++) {
        int m = m0 + wm + i * 16 + quad * 4 + r;
        Co[(size_t)m * 1024 + n] = acc[i][j][r] + bias;
      }
  }
}

// ---------------------------------------------------------------- flash attention
// Block = 512 threads (8 waves), Q-tile PAIR (qt=p, 31-p). Waves 0-3 own the
// LONG stream (qt=31-p, active all nB steps), waves 4-7 the SHORT one (qt=p,
// active nS=p+1 steps). S^T = mfma(K,Q) (lane&15=q), fixed-max softmax (m=11,
// no cross-lane reduces), per-wave P^T LDS roundtrip, PV = mfma(V^T, P^T)
// accumulating O^T; l = scalar/lane reduced once at end.
__global__ __launch_bounds__(512, 4) void flash_kernel(
    const unsigned short* __restrict__ Qg, const unsigned short* __restrict__ Kg,
    const unsigned short* __restrict__ Vg, unsigned short* __restrict__ Og) {
  const int p = blockIdx.x;                 // 0..15
  const int bh = blockIdx.y;
  const int tid = threadIdx.x, wave = tid >> 6, lane = tid & 63;
  const int lr = lane & 15, quad = lane >> 4;
  __shared__ __align__(16) unsigned short sK[2][4096];
  __shared__ __align__(16) unsigned short sV[2][4096];
  __shared__ __align__(16) unsigned short sP[8][1024];   // per-wave P^T buffer
  const size_t base = (size_t)bh * (TT * 64);
  const int st = wave >> 2;                 // 0 = long stream, 1 = short stream
  const int qt = st ? p : (31 - p);
  const int nS = st ? (p + 1) : (32 - p);   // active steps for this wave
  const int nB = 32 - p;                    // block step count (long stream)
  const int qg = qt * 64 + (wave & 3) * 16 + lr;   // this lane's q row
  const f32x4 zero = {0.f, 0.f, 0.f, 0.f};

  bfrag qf0, qf1;
  {
    const unsigned short* qr = Qg + base + (size_t)qg * 64;
    qf0 = *(const bfrag*)(qr + quad * 8);
    qf1 = *(const bfrag*)(qr + 32 + quad * 8);
  }
  f32x4 o[4];
  float rs = 0.f;
#pragma unroll
  for (int j = 0; j < 4; j++) o[j] = zero;

  const unsigned short* kgb = Kg + base;
  const unsigned short* vgb = Vg + base;

  // stage tile 0 into buf 0: each of 8 waves stages 1KB of K and 1KB of V
  {
    int fb = wave * 512;
    async16(kgb + fb + lane * 8, &sK[0][fb]);
    async16(vgb + fb + lane * 8, &sV[0][fb]);
  }

  unsigned short* sPw = sP[wave];
  const int pwr = lr * 8 + (quad & 1) * 4;  // P-write column part
  const int pq2 = quad >> 1;

  for (int kt = 0; kt < nB; ++kt) {
    const int buf = kt & 1;
    __syncthreads();                        // staged tile kt ready; prev compute done
    if (kt + 1 < nB) {                      // prefetch next tile into other buffer
      int fb = wave * 512;
      const size_t g = (size_t)(kt + 1) * 4096 + fb + lane * 8;
      async16(kgb + g, &sK[buf ^ 1][fb]);
      async16(vgb + g, &sV[buf ^ 1][fb]);
    }
    if (kt < nS) {                          // wave-uniform; short-stream waves idle late
      // S^T: lane&15 = q, rows = keys
      f32x4 sT[4];
#pragma unroll
      for (int ct = 0; ct < 4; ct++) {
        int row8 = (ct * 16 + lr) * 8;
        bfrag k0 = *(const bfrag*)&sK[buf][quad * 512 + row8];
        bfrag k1 = *(const bfrag*)&sK[buf][(4 + quad) * 512 + row8];
        f32x4 t = __builtin_amdgcn_mfma_f32_16x16x32_bf16(k0, qf0, zero, 0, 0, 0);
        sT[ct]  = __builtin_amdgcn_mfma_f32_16x16x32_bf16(k1, qf1, t,    0, 0, 0);
      }
      const bool diag = (kt == nS - 1);
#pragma unroll
      for (int ct = 0; ct < 4; ++ct) {
        float e[4];
#pragma unroll
        for (int r = 0; r < 4; ++r)
          e[r] = __expf(sT[ct][r] - 11.0f);   // fixed max m=11
        if (diag) {
#pragma unroll
          for (int r = 0; r < 4; ++r) {
            int key = kt * 64 + ct * 16 + quad * 4 + r;
            if (key > qg) e[r] = 0.f;
          }
        }
        rs += (e[0] + e[1]) + (e[2] + e[3]);
        uint2 w;
        w.x = pack2bf(e[0], e[1]);
        w.y = pack2bf(e[2], e[3]);
        *(uint2*)&sPw[(ct * 2 + pq2) * 128 + pwr] = w;   // P^T chunk-major
      }
      bfrag pf0 = *(const bfrag*)&sPw[quad * 128 + lr * 8];        // keys 0-31
      bfrag pf1 = *(const bfrag*)&sPw[(4 + quad) * 128 + lr * 8];  // keys 32-63
#pragma unroll
      for (int j = 0; j < 4; j++) {
        int row8 = (j * 16 + lr) * 8;
        bfrag v0 = *(const bfrag*)&sV[buf][quad * 512 + row8];     // A-frag m=d
        bfrag v1 = *(const bfrag*)&sV[buf][(4 + quad) * 512 + row8];
        o[j] = __builtin_amdgcn_mfma_f32_16x16x32_bf16(v0, pf0, o[j], 0, 0, 0);
        o[j] = __builtin_amdgcn_mfma_f32_16x16x32_bf16(v1, pf1, o[j], 0, 0, 0);
      }
    }
  }

  // final l reduce across quads (lanes lr, lr+16, lr+32, lr+48 share q)
  rs += __shfl_xor(rs, 16); rs += __shfl_xor(rs, 32);
  const float inv = 1.0f / rs;

  // epilogue: O^T (lane=q, regs=d) -> (B,T,D) bf16, 8B packed stores
  const int b = bh >> 4, h = bh & 15;
#pragma unroll
  for (int j = 0; j < 4; j++) {
    ushort4 pk;
    pk.x = f2bf_hw(o[j][0] * inv); pk.y = f2bf_hw(o[j][1] * inv);
    pk.z = f2bf_hw(o[j][2] * inv); pk.w = f2bf_hw(o[j][3] * inv);
    int col = h * 64 + j * 16 + quad * 4;
    *(ushort4*)(Og + (size_t)(b * TT + qg) * 1024 + col) = pk;
  }
}

// ---------------------------------------------------------------- launch
extern "C" void kernel_launch(void* const* d_in, const int* in_sizes, int n_in,
                              void* d_out, int out_size, void* d_ws, size_t ws_size,
                              hipStream_t stream) {
  const float* x  = (const float*)d_in[0];
  const float* Wq = (const float*)d_in[1];
  const float* bq = (const float*)d_in[2];
  const float* Wk = (const float*)d_in[3];
  const float* bk = (const float*)d_in[4];
  const float* Wv = (const float*)d_in[5];
  const float* bv = (const float*)d_in[6];
  const float* Wo = (const float*)d_in[7];
  const float* bo = (const float*)d_in[8];
  float* out = (float*)d_out;

  unsigned short* ws = (unsigned short*)d_ws;
  unsigned short* xb   = ws;                                // 4M elems
  unsigned short* wqkv = ws + (size_t)4 * 1024 * 1024;      // 3M
  unsigned short* wob  = ws + (size_t)7 * 1024 * 1024;      // 1M
  unsigned short* Qb   = ws + (size_t)8 * 1024 * 1024;      // 4M
  unsigned short* Kb   = ws + (size_t)12 * 1024 * 1024;     // 4M
  unsigned short* Vb   = ws + (size_t)16 * 1024 * 1024;     // 4M
  unsigned short* Ob   = ws + (size_t)20 * 1024 * 1024;     // 4M -> 48MB total

  cvt_kernel<<<dim3(8192), dim3(256), 0, stream>>>(x, Wq, Wk, Wv, Wo, xb, wqkv, wob);
  gemm_bt<0, 128><<<dim3(24, 32), dim3(256), 0, stream>>>(xb, wqkv, bq, bk, bv,
                                                          Qb, Kb, Vb, (float*)nullptr);
  flash_kernel<<<dim3(16, 32), dim3(512), 0, stream>>>(Qb, Kb, Vb, Ob);
  gemm_op<<<dim3(8, 64), dim3(256), 0, stream>>>(Ob, wob, bo, out);
}

// Round 10
// 186.890 us; speedup vs baseline: 1.0401x; 1.0271x over previous
//
#include <hip/hip_runtime.h>
#include <stdint.h>

#define DM 1024
#define NH 16
#define HD 64
#define BB 2
#define TT 2048
#define MT (BB*TT)   // 4096 rows total

typedef __bf16 bfrag __attribute__((ext_vector_type(8)));     // 8 bf16 = 4 VGPR (MFMA A/B)
typedef float  f32x4 __attribute__((ext_vector_type(4)));     // MFMA C/D

__device__ __forceinline__ unsigned short f2bf(float f) {
  union { float f; unsigned u; } v; v.f = f;
  unsigned r = v.u + 0x7fffu + ((v.u >> 16) & 1u);  // RNE
  return (unsigned short)(r >> 16);
}

__device__ __forceinline__ unsigned short f2bf_hw(float f) {
  __bf16 b = (__bf16)f;                 // hardware cvt
  union { __bf16 b; unsigned short u; } v; v.b = b;
  return v.u;
}

__device__ __forceinline__ unsigned int pack2bf(float a, float b) {
  union { __bf16 h[2]; unsigned int u; } v;
  v.h[0] = (__bf16)a; v.h[1] = (__bf16)b;   // fuses to v_cvt_pk_bf16_f32
  return v.u;
}

__device__ __forceinline__ void async16(const void* g, void* l) {
  __builtin_amdgcn_global_load_lds(
      (const __attribute__((address_space(1))) unsigned int*)g,
      (__attribute__((address_space(3))) unsigned int*)l, 16, 0, 0);
}

// ---------------------------------------------------------------- cvt fp32->bf16
__global__ __launch_bounds__(256) void cvt_kernel(
    const float* __restrict__ x,  const float* __restrict__ Wq,
    const float* __restrict__ Wk, const float* __restrict__ Wv,
    const float* __restrict__ Wo,
    unsigned short* __restrict__ xb, unsigned short* __restrict__ wqkv,
    unsigned short* __restrict__ wob) {
  int i = blockIdx.x * 256 + threadIdx.x;       // one float4 group each
  const int NX = MT * DM / 4;                   // 1048576 groups of x
  const int NW = DM * DM / 4;                   // 262144 per weight
  const float* src; unsigned short* dst; int off;
  if      (i < NX)        { src = x;  dst = xb;              off = i; }
  else if (i < NX + NW)   { src = Wq; dst = wqkv;            off = i - NX; }
  else if (i < NX + 2*NW) { src = Wk; dst = wqkv + DM*DM;    off = i - NX - NW; }
  else if (i < NX + 3*NW) { src = Wv; dst = wqkv + 2*DM*DM;  off = i - NX - 2*NW; }
  else                    { src = Wo; dst = wob;             off = i - NX - 3*NW; }
  float4 v = ((const float4*)src)[off];
  ushort4 o;
  o.x = f2bf(v.x); o.y = f2bf(v.y); o.z = f2bf(v.z); o.w = f2bf(v.w);
  ((ushort4*)dst)[off] = o;
}

// ---------------------------------------------------------------- QKV GEMM (r5-exact)
// C = A * B^T, 128x128 tile, BK=32, dbuf LDS, ONE barrier per K-step.
// Bank swizzle chunk = quad ^ ((row>>1)&3) (conflict-free, measured r5/r8).
template<int EPI, int TM>
__global__ __launch_bounds__(256) void gemm_bt(
    const unsigned short* __restrict__ A, const unsigned short* __restrict__ Bm,
    const float* __restrict__ bias0, const float* __restrict__ bias1,
    const float* __restrict__ bias2,
    unsigned short* __restrict__ Qo, unsigned short* __restrict__ Ko,
    unsigned short* __restrict__ Vo, float* __restrict__ Co) {
  constexpr int WM = TM / 2;       // rows per wave
  constexpr int MI = WM / 16;      // acc tiles along M
  const int tid = threadIdx.x;
  const int wave = tid >> 6, lane = tid & 63;
  const int lr = lane & 15, quad = lane >> 4;
  const int m0 = blockIdx.y * TM, n0 = blockIdx.x * 128;
  __shared__ __align__(16) unsigned short sA[2][TM * 32];
  __shared__ __align__(16) unsigned short sB[2][128 * 32];
  const f32x4 zero = {0.f, 0.f, 0.f, 0.f};
  f32x4 acc[MI][4];
#pragma unroll
  for (int i = 0; i < MI; i++)
#pragma unroll
    for (int j = 0; j < 4; j++) acc[i][j] = zero;
  const int wm = (wave >> 1) * WM, wn = (wave & 1) * 64;

  auto stage = [&](int kt, int buf) {
    const int k0 = kt * 32;
#pragma unroll
    for (int rep = 0; rep < TM / 64; ++rep) {
      int fb = rep * 2048 + wave * 512;     // wave-uniform LDS base (elements)
      int fl = fb + lane * 8;
      int row = fl >> 5;
      int c   = (fl >> 3) & 3;
      int col = ((c ^ ((row >> 1) & 3)) << 3);  // bank swizzle folded into gaddr
      async16(A + (size_t)(m0 + row) * 1024 + k0 + col, &sA[buf][fb]);
    }
#pragma unroll
    for (int rep = 0; rep < 2; ++rep) {
      int fb = rep * 2048 + wave * 512;
      int fl = fb + lane * 8;
      int row = fl >> 5;
      int c   = (fl >> 3) & 3;
      int col = ((c ^ ((row >> 1) & 3)) << 3);
      async16(Bm + (size_t)(n0 + row) * 1024 + k0 + col, &sB[buf][fb]);
    }
  };

  stage(0, 0);
  for (int kt = 0; kt < 32; ++kt) {
    const int buf = kt & 1;
    __syncthreads();                 // staged tile kt visible; prev compute done
    if (kt + 1 < 32) stage(kt + 1, buf ^ 1);
    bfrag af[MI], bfr[4];
#pragma unroll
    for (int i = 0; i < MI; i++) {
      int ra = wm + i * 16 + lr;
      af[i]  = *(const bfrag*)&sA[buf][ra * 32 + ((quad ^ ((ra >> 1) & 3)) << 3)];
    }
#pragma unroll
    for (int j = 0; j < 4; j++) {
      int rb = wn + j * 16 + lr;
      bfr[j] = *(const bfrag*)&sB[buf][rb * 32 + ((quad ^ ((rb >> 1) & 3)) << 3)];
    }
#pragma unroll
    for (int i = 0; i < MI; i++)
#pragma unroll
      for (int j = 0; j < 4; j++)
        acc[i][j] = __builtin_amdgcn_mfma_f32_16x16x32_bf16(af[i], bfr[j], acc[i][j], 0, 0, 0);
  }

  if (EPI == 0) {
    // n in [0,3072): qkv = n>>10; head h = (n&1023)>>6; d = n&63
#pragma unroll
    for (int j = 0; j < 4; j++) {
      int n = n0 + wn + j * 16 + lr;
      int qkv = n >> 10, nn = n & 1023;
      float bias = (qkv == 0 ? bias0 : qkv == 1 ? bias1 : bias2)[nn];
      int h = nn >> 6, d = nn & 63;
      if (qkv == 2) {
        // V: no rotary; fragment-order layout, pack 4 consecutive keys (r) per store
#pragma unroll
        for (int i = 0; i < MI; i++) {
          int t0 = m0 + wm + i * 16 + quad * 4;
          int b = t0 >> 11, tt = t0 & 2047;
          size_t bb = (size_t)((b << 4) + h) * (TT * 64);
          int kk0 = tt & 63;
          size_t off = bb + (size_t)(tt >> 6) * 4096 +
                       (size_t)((kk0 >> 3) << 9) + (d << 3) + (kk0 & 7);
          ushort4 pk;
          pk.x = f2bf(acc[i][j][0] + bias);
          pk.y = f2bf(acc[i][j][1] + bias);
          pk.z = f2bf(acc[i][j][2] + bias);
          pk.w = f2bf(acc[i][j][3] + bias);
          *(ushort4*)(Vo + off) = pk;
        }
      } else {
#pragma unroll
        for (int i = 0; i < MI; i++)
#pragma unroll
          for (int r = 0; r < 4; r++) {
            int m = m0 + wm + i * 16 + quad * 4 + r;
            float vb = acc[i][j][r] + bias;
            // rotary pair (d^1) lives in lane^1 (same row, adjacent column)
            float pv = __shfl_xor(vb, 1);
            float val = (n & 1) ? pv : -pv;
            int b = m >> 11, t = m & 2047;
            size_t base = (size_t)((b << 4) + h) * (TT * 64);
            if (qkv == 0) {                       // Q: plain (B,H,T,64), pre-scaled
              Qo[base + (size_t)t * 64 + d] = f2bf(val * 0.125f);
            } else {                              // K: fragment-order per 64-row tile
              int kk = t & 63;
              size_t off = base + (size_t)(t >> 6) * 4096 +
                           (size_t)((d >> 3) << 9) + (kk << 3) + (d & 7);
              Ko[off] = f2bf(val);
            }
          }
      }
    }
  } else {
#pragma unroll
    for (int j = 0; j < 4; j++) {
      int n = n0 + wn + j * 16 + lr;
      float bias = bias0[n];
#pragma unroll
      for (int i = 0; i < MI; i++)
#pragma unroll
        for (int r = 0; r < 4; r++) {
          int m = m0 + wm + i * 16 + quad * 4 + r;
          Co[(size_t)m * 1024 + n] = acc[i][j][r] + bias;
        }
    }
  }
}

// ---------------------------------------------------------------- out-proj GEMM (r9)
// C = A * B^T + bias, fp32 out. 64x128 tile, BK=64, 16 barriers.
__global__ __launch_bounds__(256) void gemm_op(
    const unsigned short* __restrict__ A, const unsigned short* __restrict__ Bm,
    const float* __restrict__ bias0, float* __restrict__ Co) {
  const int tid = threadIdx.x;
  const int wave = tid >> 6, lane = tid & 63;
  const int lr = lane & 15, quad = lane >> 4;
  const int m0 = blockIdx.y * 64, n0 = blockIdx.x * 128;
  __shared__ __align__(16) unsigned short sA[2][64 * 64];
  __shared__ __align__(16) unsigned short sB[2][128 * 64];
  const f32x4 zero = {0.f, 0.f, 0.f, 0.f};
  f32x4 acc[2][4];
#pragma unroll
  for (int i = 0; i < 2; i++)
#pragma unroll
    for (int j = 0; j < 4; j++) acc[i][j] = zero;
  const int wm = (wave >> 1) * 32, wn = (wave & 1) * 64;

  auto swz = [](int row) { return ((row & 1) << 2) | ((row >> 1) & 3); };

  auto stage = [&](int kt, int buf) {
    const int k0 = kt * 64;
#pragma unroll
    for (int rep = 0; rep < 2; ++rep) {       // A: 64 rows x 64
      int fb = rep * 2048 + wave * 512;
      int fl = fb + lane * 8;
      int row = fl >> 6, pc = (fl >> 3) & 7;
      async16(A + (size_t)(m0 + row) * 1024 + k0 + ((pc ^ swz(row)) << 3), &sA[buf][fb]);
    }
#pragma unroll
    for (int rep = 0; rep < 4; ++rep) {       // B: 128 rows x 64
      int fb = rep * 2048 + wave * 512;
      int fl = fb + lane * 8;
      int row = fl >> 6, pc = (fl >> 3) & 7;
      async16(Bm + (size_t)(n0 + row) * 1024 + k0 + ((pc ^ swz(row)) << 3), &sB[buf][fb]);
    }
  };

  stage(0, 0);
  for (int kt = 0; kt < 16; ++kt) {
    const int buf = kt & 1;
    __syncthreads();                 // staged tile kt visible; prev compute done
    if (kt + 1 < 16) stage(kt + 1, buf ^ 1);
#pragma unroll
    for (int ks = 0; ks < 2; ++ks) {          // two 32-K windows per staged tile
      bfrag af[2], bfr[4];
#pragma unroll
      for (int i = 0; i < 2; i++) {
        int ra = wm + i * 16 + lr;
        af[i] = *(const bfrag*)&sA[buf][ra * 64 + (((ks * 4 + quad) ^ swz(ra)) << 3)];
      }
#pragma unroll
      for (int j = 0; j < 4; j++) {
        int rb = wn + j * 16 + lr;
        bfr[j] = *(const bfrag*)&sB[buf][rb * 64 + (((ks * 4 + quad) ^ swz(rb)) << 3)];
      }
#pragma unroll
      for (int i = 0; i < 2; i++)
#pragma unroll
        for (int j = 0; j < 4; j++)
          acc[i][j] = __builtin_amdgcn_mfma_f32_16x16x32_bf16(af[i], bfr[j], acc[i][j], 0, 0, 0);
    }
  }

#pragma unroll
  for (int j = 0; j < 4; j++) {
    int n = n0 + wn + j * 16 + lr;
    float bias = bias0[n];
#pragma unroll
    for (int i = 0; i < 2; i++)
#pragma unroll
      for (int r = 0; r < 4; r++) {
        int m = m0 + wm + i * 16 + quad * 4 + r;
        Co[(size_t)m * 1024 + n] = acc[i][j][r] + bias;
      }
  }
}

// ---------------------------------------------------------------- flash attention
// Block = 512 threads (8 waves), Q-tile PAIR (qt=p, 31-p); waves 0-3 = long
// stream, 4-7 = short. Bc=128: each barrier stages TWO 64-key tiles (contiguous
// in the fragment-order layout) and the 64-key body runs twice between barriers
// -> barriers per block drop 17-32 to 9-17, and the vmcnt drain at each barrier
// waits on loads issued a full double compute-phase earlier (fully landed).
// LDS 80 KB -> exactly 2 blocks/CU at 512 thr. S^T = mfma(K,Q) (lane&15=q),
// fixed-max softmax (m=11), per-wave P^T LDS roundtrip, PV = mfma(V^T,P^T).
__global__ __launch_bounds__(512, 4) void flash_kernel(
    const unsigned short* __restrict__ Qg, const unsigned short* __restrict__ Kg,
    const unsigned short* __restrict__ Vg, unsigned short* __restrict__ Og) {
  const int p = blockIdx.x;                 // 0..15
  const int bh = blockIdx.y;
  const int tid = threadIdx.x, wave = tid >> 6, lane = tid & 63;
  const int lr = lane & 15, quad = lane >> 4;
  __shared__ __align__(16) unsigned short sK[2][8192];
  __shared__ __align__(16) unsigned short sV[2][8192];
  __shared__ __align__(16) unsigned short sP[8][1024];   // per-wave P^T buffer
  const size_t base = (size_t)bh * (TT * 64);
  const int st = wave >> 2;                 // 0 = long stream, 1 = short stream
  const int qt = st ? p : (31 - p);
  const int nS = st ? (p + 1) : (32 - p);   // active 64-key tiles for this wave
  const int nB = 32 - p;                    // long-stream tile count
  const int npair = (nB + 1) >> 1;          // 128-key steps
  const int qg = qt * 64 + (wave & 3) * 16 + lr;   // this lane's q row
  const f32x4 zero = {0.f, 0.f, 0.f, 0.f};

  bfrag qf0, qf1;
  {
    const unsigned short* qr = Qg + base + (size_t)qg * 64;
    qf0 = *(const bfrag*)(qr + quad * 8);
    qf1 = *(const bfrag*)(qr + 32 + quad * 8);
  }
  f32x4 o[4];
  float rs = 0.f;
#pragma unroll
  for (int j = 0; j < 4; j++) o[j] = zero;

  const unsigned short* kgb = Kg + base;
  const unsigned short* vgb = Vg + base;

  // stage pair 0 (tiles 0,1) into buf 0: 8 waves x 2 reps x 1KB each for K and V
#pragma unroll
  for (int rep = 0; rep < 2; ++rep) {
    int fb = rep * 4096 + wave * 512;
    async16(kgb + fb + lane * 8, &sK[0][fb]);
    async16(vgb + fb + lane * 8, &sV[0][fb]);
  }

  const int pwr = lr * 8 + (quad & 1) * 4;  // P-write column part
  const int pq2 = quad >> 1;

  for (int ktb = 0; ktb < npair; ++ktb) {
    const int buf = ktb & 1;
    __syncthreads();                        // staged pair ktb ready; prev compute done
    if (ktb + 1 < npair) {                  // prefetch next pair (in-bounds even if
#pragma unroll                              //  last pair is half: tile idx <= 31)
      for (int rep = 0; rep < 2; ++rep) {
        int fb = rep * 4096 + wave * 512;
        const size_t g = (size_t)(ktb + 1) * 8192 + fb + lane * 8;
        async16(kgb + g, &sK[buf ^ 1][fb]);
        async16(vgb + g, &sV[buf ^ 1][fb]);
      }
    }
#pragma unroll
    for (int sub = 0; sub < 2; ++sub) {
      const int kt = ktb * 2 + sub;
      if (kt < nS) {                        // wave-uniform activity guard
        const int hb = sub * 4096;          // 64-key half within the staged pair
        // S^T: lane&15 = q, rows = keys
        f32x4 sT[4];
#pragma unroll
        for (int ct = 0; ct < 4; ct++) {
          int row8 = (ct * 16 + lr) * 8;
          bfrag k0 = *(const bfrag*)&sK[buf][hb + quad * 512 + row8];
          bfrag k1 = *(const bfrag*)&sK[buf][hb + (4 + quad) * 512 + row8];
          f32x4 t = __builtin_amdgcn_mfma_f32_16x16x32_bf16(k0, qf0, zero, 0, 0, 0);
          sT[ct]  = __builtin_amdgcn_mfma_f32_16x16x32_bf16(k1, qf1, t,    0, 0, 0);
        }
        const bool diag = (kt == nS - 1);
#pragma unroll
        for (int ct = 0; ct < 4; ++ct) {
          float e[4];
#pragma unroll
          for (int r = 0; r < 4; ++r)
            e[r] = __expf(sT[ct][r] - 11.0f);   // fixed max m=11
          if (diag) {
#pragma unroll
            for (int r = 0; r < 4; ++r) {
              int key = kt * 64 + ct * 16 + quad * 4 + r;
              if (key > qg) e[r] = 0.f;
            }
          }
          rs += (e[0] + e[1]) + (e[2] + e[3]);
          uint2 w;
          w.x = pack2bf(e[0], e[1]);
          w.y = pack2bf(e[2], e[3]);
          *(uint2*)&sP[wave][(ct * 2 + pq2) * 128 + pwr] = w;   // P^T chunk-major
        }
        bfrag pf0 = *(const bfrag*)&sP[wave][quad * 128 + lr * 8];        // keys 0-31
        bfrag pf1 = *(const bfrag*)&sP[wave][(4 + quad) * 128 + lr * 8];  // keys 32-63
#pragma unroll
        for (int j = 0; j < 4; j++) {
          int row8 = (j * 16 + lr) * 8;
          bfrag v0 = *(const bfrag*)&sV[buf][hb + quad * 512 + row8];     // A-frag m=d
          bfrag v1 = *(const bfrag*)&sV[buf][hb + (4 + quad) * 512 + row8];
          o[j] = __builtin_amdgcn_mfma_f32_16x16x32_bf16(v0, pf0, o[j], 0, 0, 0);
          o[j] = __builtin_amdgcn_mfma_f32_16x16x32_bf16(v1, pf1, o[j], 0, 0, 0);
        }
      }
    }
  }

  // final l reduce across quads (lanes lr, lr+16, lr+32, lr+48 share q)
  rs += __shfl_xor(rs, 16); rs += __shfl_xor(rs, 32);
  const float inv = 1.0f / rs;

  // epilogue: O^T (lane=q, regs=d) -> (B,T,D) bf16, 8B packed stores
  const int b = bh >> 4, h = bh & 15;
#pragma unroll
  for (int j = 0; j < 4; j++) {
    ushort4 pk;
    pk.x = f2bf_hw(o[j][0] * inv); pk.y = f2bf_hw(o[j][1] * inv);
    pk.z = f2bf_hw(o[j][2] * inv); pk.w = f2bf_hw(o[j][3] * inv);
    int col = h * 64 + j * 16 + quad * 4;
    *(ushort4*)(Og + (size_t)(b * TT + qg) * 1024 + col) = pk;
  }
}

// ---------------------------------------------------------------- launch
extern "C" void kernel_launch(void* const* d_in, const int* in_sizes, int n_in,
                              void* d_out, int out_size, void* d_ws, size_t ws_size,
                              hipStream_t stream) {
  const float* x  = (const float*)d_in[0];
  const float* Wq = (const float*)d_in[1];
  const float* bq = (const float*)d_in[2];
  const float* Wk = (const float*)d_in[3];
  const float* bk = (const float*)d_in[4];
  const float* Wv = (const float*)d_in[5];
  const float* bv = (const float*)d_in[6];
  const float* Wo = (const float*)d_in[7];
  const float* bo = (const float*)d_in[8];
  float* out = (float*)d_out;

  unsigned short* ws = (unsigned short*)d_ws;
  unsigned short* xb   = ws;                                // 4M elems
  unsigned short* wqkv = ws + (size_t)4 * 1024 * 1024;      // 3M
  unsigned short* wob  = ws + (size_t)7 * 1024 * 1024;      // 1M
  unsigned short* Qb   = ws + (size_t)8 * 1024 * 1024;      // 4M
  unsigned short* Kb   = ws + (size_t)12 * 1024 * 1024;     // 4M
  unsigned short* Vb   = ws + (size_t)16 * 1024 * 1024;     // 4M
  unsigned short* Ob   = ws + (size_t)20 * 1024 * 1024;     // 4M -> 48MB total

  cvt_kernel<<<dim3(8192), dim3(256), 0, stream>>>(x, Wq, Wk, Wv, Wo, xb, wqkv, wob);
  gemm_bt<0, 128><<<dim3(24, 32), dim3(256), 0, stream>>>(xb, wqkv, bq, bk, bv,
                                                          Qb, Kb, Vb, (float*)nullptr);
  flash_kernel<<<dim3(16, 32), dim3(512), 0, stream>>>(Qb, Kb, Vb, Ob);
  gemm_op<<<dim3(8, 64), dim3(256), 0, stream>>>(Ob, wob, bo, out);
}